// Round 16
// baseline (1392.553 us; speedup 1.0000x reference)
//
#include <hip/hip_runtime.h>
#include <hip/hip_bf16.h>
#include <math.h>

#define B_   64
#define T_   512
#define F_   256
#define ENC_ 256
#define P_   128
#define H_   256
#define K_   12
#define INV_TEMP 10.0f

typedef unsigned short u16;
typedef _Float16 half2v __attribute__((ext_vector_type(2)));
union U2H { unsigned int u; half2v h; };
typedef __attribute__((ext_vector_type(8))) short bf16x8;   // 8 bf16 = 4 VGPRs
typedef __attribute__((ext_vector_type(4))) float f32x4;    // MFMA C/D
union BF8 { bf16x8 v; u16 e[8]; };

// ---------------- helpers ----------------------------------------------------
__device__ __forceinline__ float rcpf(float x) {
#if __has_builtin(__builtin_amdgcn_rcpf)
    return __builtin_amdgcn_rcpf(x);
#else
    return 1.f / x;
#endif
}
__device__ __forceinline__ u16 f2bf(float f) {   // RNE
    unsigned int u = __float_as_uint(f);
    unsigned int r = (u + 0x7fffu + ((u >> 16) & 1u)) >> 16;
    return (u16)r;
}
__device__ __forceinline__ float bf2f(u16 v) {
    return __uint_as_float(((unsigned int)v) << 16);
}
__device__ __forceinline__ float bflo(unsigned int u) { return __uint_as_float(u << 16); }
__device__ __forceinline__ float bfhi(unsigned int u) { return __uint_as_float(u & 0xffff0000u); }
// f32 -> e5m2 byte (RNE via f16; e5m2 = top byte of f16)
__device__ __forceinline__ unsigned f2e5(float f) {
    U2H c; c.h.x = (_Float16)f; c.h.y = (_Float16)0.f;
    unsigned h = c.u & 0xFFFFu;
    return ((h + 0x7Fu + ((h >> 8) & 1u)) >> 8) & 0xFFu;
}
// f32 -> OCP e4m3fn byte (RNE, subnormals, sat to 448)
__device__ __forceinline__ unsigned f2e4(float f) {
#if __has_builtin(__builtin_amdgcn_cvt_pk_fp8_f32)
    return (unsigned)__builtin_amdgcn_cvt_pk_fp8_f32(f, f, 0, false) & 0xFFu;
#else
    unsigned u = __float_as_uint(f);
    unsigned s = (u >> 24) & 0x80u;
    int e = (int)((u >> 23) & 0xFF) - 127;
    unsigned m = u & 0x7FFFFFu;
    if (e >= 9) return s | 0x7Eu;
    if (e >= -6) {
        unsigned mant = m >> 20, rest = m & 0xFFFFFu;
        if (rest > 0x80000u || (rest == 0x80000u && (mant & 1u))) mant++;
        unsigned v = ((unsigned)(e + 7) << 3) + mant;
        if (v > 0x7Eu) v = 0x7Eu;
        return s | v;
    }
    if (e < -10) return s;
    unsigned full = 0x800000u | m;
    int shift = 20 + (-6 - e);
    unsigned mant = full >> shift;
    unsigned rem = full & ((1u << shift) - 1u);
    unsigned half = 1u << (shift - 1);
    if (rem > half || (rem == half && (mant & 1u))) mant++;
    return s | mant;
#endif
}
__device__ __forceinline__ float wave_sum(float v) {
    #pragma unroll
    for (int o = 32; o > 0; o >>= 1) v += __shfl_down(v, o, 64);
    return v;
}
__device__ __host__ __forceinline__ int wtile(int wv, int s) {   // wave's s-th owned n-tile
    return (s < 2) ? (2 * wv + s) : (s < 4) ? (16 + 2 * wv + s - 2) : (32 + 2 * wv + s - 4);
}

// ---------------- merged setup: conversions + fold + accum zero + Wq ---------
// 0..95 Wit; 96..479 Wpt; 480..608 fold+accum; 609..704 Wq (e5m2 B-fragments)
__global__ __launch_bounds__(256) void setup_conv(const float* __restrict__ Wh,
                                                  const float* __restrict__ Wi,
                                                  u16* __restrict__ Wit,
                                                  const float* __restrict__ Wp,
                                                  u16* __restrict__ Wpt,
                                                  const float* __restrict__ We,
                                                  const float* __restrict__ be,
                                                  const float* __restrict__ Wpj,
                                                  const float* __restrict__ bpj,
                                                  u16* __restrict__ Wct,
                                                  float* __restrict__ bc,
                                                  float* __restrict__ accum,
                                                  uint2* __restrict__ Wq) {
    int bid = blockIdx.x;
    if (bid < 96) {
        __shared__ float tile[32][33];
        int b2 = bid;
        int n0 = (b2 % 24) * 32, k0 = (b2 / 24) * 32;
        int tx = threadIdx.x & 31, ty = threadIdx.x >> 5;
        #pragma unroll
        for (int i = 0; i < 32; i += 8)
            tile[ty + i][tx] = Wi[(size_t)(k0 + ty + i) * 768 + n0 + tx];
        __syncthreads();
        #pragma unroll
        for (int i = 0; i < 32; i += 8)
            Wit[(size_t)(n0 + ty + i) * 128 + k0 + tx] = f2bf(tile[tx][ty + i]);
    } else if (bid < 480) {
        __shared__ float tile2[32][33];
        int b3 = bid - 96;
        int kq = b3 / 32, rem = b3 % 32;
        int h0 = (rem % 8) * 32, p0 = (rem / 8) * 32;
        int tx = threadIdx.x & 31, ty = threadIdx.x >> 5;
        #pragma unroll
        for (int i = 0; i < 32; i += 8)
            tile2[ty + i][tx] = Wp[(size_t)kq * H_ * P_ + (size_t)(h0 + ty + i) * P_ + p0 + tx];
        __syncthreads();
        #pragma unroll
        for (int i = 0; i < 32; i += 8)
            Wpt[(size_t)kq * P_ * H_ + (size_t)(p0 + ty + i) * H_ + h0 + tx] = f2bf(tile2[tx][ty + i]);
    } else if (bid < 609) {
        int f = (bid - 480) * 2 + (threadIdx.x >> 7);
        int p = threadIdx.x & 127;
        if (f < F_) {
            float a = 0.f;
            for (int e = 0; e < ENC_; e++) a = fmaf(We[f * ENC_ + e], Wpj[e * P_ + p], a);
            Wct[(size_t)p * F_ + f] = f2bf(a);
        } else if (f == F_) {
            float a = bpj[p];
            for (int e = 0; e < ENC_; e++) a = fmaf(be[e], Wpj[e * P_ + p], a);
            bc[p] = a;
        } else {
            #pragma unroll
            for (int i = 0; i < 8; i++) accum[p * 8 + i] = 0.f;
        }
    } else {
        // Wq[((wv*6+s)*8+k0)*64+lane]: 8 e5m2 bytes, k_h = k0*32+quad*8+j,
        // col = wtile(wv,s)*16 + (lane&15)
        int idx = (bid - 609) * 256 + threadIdx.x;    // 0..24575
        int lane = idx & 63;
        int rest = idx >> 6;
        int k0 = rest & 7;
        int s  = (rest >> 3) % 6;
        int wv = rest / 48;
        int col  = wtile(wv, s) * 16 + (lane & 15);
        int kh0  = k0 * 32 + (lane >> 4) * 8;
        unsigned lo = 0, hi = 0;
        #pragma unroll
        for (int j = 0; j < 4; j++)
            lo |= f2e5(Wh[(size_t)(kh0 + j) * 768 + col]) << (8 * j);
        #pragma unroll
        for (int j = 0; j < 4; j++)
            hi |= f2e5(Wh[(size_t)(kh0 + 4 + j) * 768 + col]) << (8 * j);
        Wq[idx] = make_uint2(lo, hi);
    }
}

// ---------------- MFMA GEMM, A = fp32 (converted in-register) ----------------
__global__ __launch_bounds__(256) void gemm_mfma_f32a(const float* __restrict__ A,
                                                      const u16* __restrict__ Bt,
                                                      const float* __restrict__ bias,
                                                      u16* __restrict__ Ch,
                                                      int N, int K) {
#if defined(__HIP_DEVICE_COMPILE__)
    int tid  = threadIdx.x;
    int w    = tid >> 6;
    int lane = tid & 63;
    int col  = lane & 15;
    int quad = lane >> 4;
    int bm = blockIdx.y * 64, bn = blockIdx.x * 128;

    f32x4 acc[8] = {};
    const float* arow = A + (size_t)(bm + w * 16 + col) * K;
    #pragma unroll
    for (int k0 = 0; k0 < K; k0 += 32) {
        float4 v0 = *(const float4*)(arow + k0 + quad * 8);
        float4 v1 = *(const float4*)(arow + k0 + quad * 8 + 4);
        BF8 af;
        af.e[0] = f2bf(v0.x); af.e[1] = f2bf(v0.y); af.e[2] = f2bf(v0.z); af.e[3] = f2bf(v0.w);
        af.e[4] = f2bf(v1.x); af.e[5] = f2bf(v1.y); af.e[6] = f2bf(v1.z); af.e[7] = f2bf(v1.w);
        #pragma unroll
        for (int nt = 0; nt < 8; nt++) {
            bf16x8 bf = *(const bf16x8*)(Bt + (size_t)(bn + nt * 16 + col) * K + k0 + quad * 8);
            acc[nt] = __builtin_amdgcn_mfma_f32_16x16x32_bf16(af.v, bf, acc[nt], 0, 0, 0);
        }
    }
    #pragma unroll
    for (int nt = 0; nt < 8; nt++) {
        int gn = bn + nt * 16 + col;
        float bv = bias[gn];
        #pragma unroll
        for (int r = 0; r < 4; r++) {
            int gm = bm + w * 16 + quad * 4 + r;
            Ch[(size_t)gm * N + gn] = f2bf(acc[nt][r] + bv);
        }
    }
#endif
}

// ---------------- MFMA GEMM, A = bf16, C = bf16 ------------------------------
__global__ __launch_bounds__(256) void gemm_mfma(const u16* __restrict__ A,
                                                 const u16* __restrict__ Bt,
                                                 const float* __restrict__ bias,
                                                 u16* __restrict__ Ch,
                                                 int N, int K) {
#if defined(__HIP_DEVICE_COMPILE__)
    int tid  = threadIdx.x;
    int w    = tid >> 6;
    int lane = tid & 63;
    int col  = lane & 15;
    int quad = lane >> 4;
    int bm = blockIdx.y * 64, bn = blockIdx.x * 128;

    f32x4 acc[8] = {};
    const u16* arow = A + (size_t)(bm + w * 16 + col) * K;
    #pragma unroll
    for (int k0 = 0; k0 < K; k0 += 32) {
        bf16x8 af = *(const bf16x8*)(arow + k0 + quad * 8);
        #pragma unroll
        for (int nt = 0; nt < 8; nt++) {
            bf16x8 bf = *(const bf16x8*)(Bt + (size_t)(bn + nt * 16 + col) * K + k0 + quad * 8);
            acc[nt] = __builtin_amdgcn_mfma_f32_16x16x32_bf16(af, bf, acc[nt], 0, 0, 0);
        }
    }
    #pragma unroll
    for (int nt = 0; nt < 8; nt++) {
        int gn = bn + nt * 16 + col;
        float bv = bias[gn];
        #pragma unroll
        for (int r = 0; r < 4; r++) {
            int gm = bm + w * 16 + quad * 4 + r;
            Ch[(size_t)gm * N + gn] = f2bf(acc[nt][r] + bv);
        }
    }
#endif
}

// ---------------- fp8-MFMA GRU (blocks 0..7) + zsum (blocks 8..71) -----------
// Body guarded by __HIP_DEVICE_COMPILE__: the host pass cannot see AMDGCN
// builtins (this is the r15 bug — a host-side __has_builtin picked the
// fallback launch). Host sees an empty body but a launchable symbol.
// Block g owns batches 8g..8g+7. Per step: gh = H(16x256,e4m3; rows 8-15 zero)
// @ Wh(256x768,e5m2) via 48 fp8_bf8 MFMAs/wave (8 waves). Wave w owns paired
// n-tiles {2w,2w+1,+16,+32}: each lane holds its r/z/n acc triple -> gates
// in-register, fp32 h recurrence in registers, ONE barrier/step.
__global__ __attribute__((amdgpu_flat_work_group_size(512, 512), amdgpu_waves_per_eu(2, 2)))
void gru_zsum_mfma(const u16* __restrict__ gi,
                   const long long* __restrict__ Wq,
                   const float* __restrict__ bhn,
                   u16* __restrict__ ch,
                   const u16* __restrict__ zh,
                   float* __restrict__ zsum) {
#if defined(__HIP_DEVICE_COMPILE__)
    __shared__ __align__(16) char shraw[8704];
    int tid = threadIdx.x;

    if (blockIdx.x >= 8) {
        // ---- zsum[b][p] = sum_{t=1..T-1} z[b][t][p], 16-way t-split ---------
        float (*part)[128] = (float(*)[128])shraw;
        int b   = blockIdx.x - 8;
        int pg  = tid & 31;
        int g   = tid >> 5;
        const u16* zb = zh + (size_t)b * T_ * P_;
        float s0 = 0.f, s1 = 0.f, s2 = 0.f, s3 = 0.f;
        for (int t = 1 + g; t < T_; t += 16) {
            uint2 v = *(const uint2*)(zb + (size_t)t * P_ + pg * 4);
            s0 += bflo(v.x); s1 += bfhi(v.x);
            s2 += bflo(v.y); s3 += bfhi(v.y);
        }
        part[g][pg * 4 + 0] = s0; part[g][pg * 4 + 1] = s1;
        part[g][pg * 4 + 2] = s2; part[g][pg * 4 + 3] = s3;
        __syncthreads();
        if (tid < 128) {
            float s = 0.f;
            #pragma unroll
            for (int g2 = 0; g2 < 16; g2++) s += part[g2][tid];
            zsum[(size_t)b * P_ + tid] = s;
        }
        return;
    }

    // ---- GRU ----------------------------------------------------------------
    char (*hA)[16 * 264] = (char(*)[16 * 264])shraw;   // 2 x 4224 B, stride 264
    int wv   = tid >> 6;
    int lane = tid & 63;
    int c    = lane & 15;
    int quad = lane >> 4;

    long long wq[48];
    {
        const long long* wp = Wq + (size_t)wv * 48 * 64 + lane;
        #pragma unroll
        for (int i = 0; i < 48; i++) wq[i] = wp[(size_t)i * 64];
        #pragma unroll
        for (int i = 0; i < 48; i++) asm volatile("" : "+v"(wq[i]));
    }
    // zero both h buffers (e4m3 zero = 0x00)
    for (int i = tid; i < 2 * 16 * 264 / 4; i += 512) ((unsigned*)shraw)[i] = 0u;

    int jc0 = (2 * wv + 0) * 16 + c;       // gate cols owned by this lane
    int jc1 = (2 * wv + 1) * 16 + c;
    float bh0 = bhn[jc0], bh1 = bhn[jc1];

    float hl[8];                            // fp32 h for (d, r)
    #pragma unroll
    for (int q = 0; q < 8; q++) hl[q] = 0.f;

    float pir[8], piz[8], pin[8];
    bool gact = quad < 2;
    int bg0 = blockIdx.x * 8 + quad * 4;   // first batch of this quad (if active)
    if (gact) {
        #pragma unroll
        for (int r = 0; r < 4; r++) {
            const u16* gp = gi + ((size_t)(bg0 + r) * T_) * 768;
            pir[r]     = bf2f(gp[jc0]); piz[r]     = bf2f(gp[256 + jc0]); pin[r]     = bf2f(gp[512 + jc0]);
            pir[4 + r] = bf2f(gp[jc1]); piz[4 + r] = bf2f(gp[256 + jc1]); pin[4 + r] = bf2f(gp[512 + jc1]);
        }
    }
    __syncthreads();

    int cur = 0;
    #pragma unroll 1
    for (int t = 0; t < T_; t++) {
        // MFMA phase: gh for this wave's 6 tiles
        f32x4 acc[6] = {};
        const char* hrow = hA[cur] + (size_t)c * 264 + quad * 8;   // m = c (lane&15)
        #pragma unroll
        for (int k0 = 0; k0 < 8; k0++) {
            long long av = *(const long long*)(hrow + k0 * 32);
            #pragma unroll
            for (int s = 0; s < 6; s++)
                acc[s] = __builtin_amdgcn_mfma_f32_16x16x32_fp8_bf8(av, wq[s * 8 + k0], acc[s], 0, 0, 0);
        }
        // prefetch next step's gi
        float nir[8], niz[8], nin[8];
        if (gact) {
            int tn = (t + 1 < T_) ? t + 1 : t;
            #pragma unroll
            for (int r = 0; r < 4; r++) {
                const u16* gp = gi + ((size_t)(bg0 + r) * T_ + tn) * 768;
                nir[r]     = bf2f(gp[jc0]); niz[r]     = bf2f(gp[256 + jc0]); nin[r]     = bf2f(gp[512 + jc0]);
                nir[4 + r] = bf2f(gp[jc1]); niz[4 + r] = bf2f(gp[256 + jc1]); nin[4 + r] = bf2f(gp[512 + jc1]);
            }
        }
        // gates (quads 0-1 hold acc rows quad*4+r = batches 0..7)
        if (gact) {
            char* hnxt = hA[cur ^ 1];
            #pragma unroll
            for (int d = 0; d < 2; d++) {
                int jc = d ? jc1 : jc0;
                float bh = d ? bh1 : bh0;
                #pragma unroll
                for (int r = 0; r < 4; r++) {
                    int q = d * 4 + r;
                    float gr = acc[d][r], gz = acc[2 + d][r], gn = acc[4 + d][r];
                    float rr = rcpf(1.f + __expf(-(pir[q] + gr)));
                    float zz = rcpf(1.f + __expf(-(piz[q] + gz)));
                    float xn = pin[q] + rr * (gn + bh);
                    float nn = fmaf(2.f, rcpf(1.f + __expf(-2.f * xn)), -1.f);
                    float h  = fmaf(zz, hl[q] - nn, nn);     // (1-z)n + z h
                    hl[q] = h;
                    ch[((size_t)(bg0 + r) * T_ + t) * H_ + jc] = f2bf(h);
                    hnxt[(size_t)(quad * 4 + r) * 264 + jc] = (char)f2e4(h);
                }
            }
        }
        __syncthreads();
        cur ^= 1;
        if (gact) {
            #pragma unroll
            for (int q = 0; q < 8; q++) { pir[q] = nir[q]; piz[q] = niz[q]; pin[q] = nin[q]; }
        }
    }
#endif
}

// ---------------- fused loss, MFMA; 128-row tiles; zh tiles staged in LDS ----
__global__ __launch_bounds__(512) void loss_fused(const u16* __restrict__ ch,
                                                  const u16* __restrict__ Wpt,
                                                  const float* __restrict__ bp,
                                                  const u16* __restrict__ zh,
                                                  const float* __restrict__ zsum,
                                                  float* __restrict__ accum) {
#if defined(__HIP_DEVICE_COMPILE__)
    __shared__ u16 Pst[128][136];
    __shared__ u16 Zt[64][136];
    __shared__ float sS[128];
    __shared__ float red[8];
    int k  = blockIdx.z + 1;
    int b  = blockIdx.y;
    int t0 = blockIdx.x * 128;
    int Tk = T_ - k;
    int tid  = threadIdx.x;
    int w    = tid >> 6;
    int lane = tid & 63;
    int col  = lane & 15;
    int quad = lane >> 4;
    const u16* zb = zh + (size_t)b * T_ * P_;

    if (tid < 128) {
        float s = zsum[(size_t)b * P_ + tid];
        for (int t = 1; t < k; t++) s -= bf2f(zb[(size_t)t * P_ + tid]);
        sS[tid] = s;
    }

    {
        f32x4 acc[8] = {};
        const u16* arow = ch + ((size_t)b * T_ + t0 + w * 16 + col) * H_;
        const u16* wk   = Wpt + (size_t)(k - 1) * P_ * H_;
        #pragma unroll
        for (int k0 = 0; k0 < 8; k0++) {
            bf16x8 af = *(const bf16x8*)(arow + k0 * 32 + quad * 8);
            #pragma unroll
            for (int nt = 0; nt < 8; nt++) {
                bf16x8 bf = *(const bf16x8*)(wk + (size_t)(nt * 16 + col) * H_ + k0 * 32 + quad * 8);
                acc[nt] = __builtin_amdgcn_mfma_f32_16x16x32_bf16(af, bf, acc[nt], 0, 0, 0);
            }
        }
        #pragma unroll
        for (int nt = 0; nt < 8; nt++) {
            float bias = bp[(size_t)(k - 1) * P_ + nt * 16 + col];
            #pragma unroll
            for (int r = 0; r < 4; r++)
                Pst[w * 16 + quad * 4 + r][nt * 16 + col] = f2bf(acc[nt][r] + bias);
        }
    }
    __syncthreads();

    float mloc[4], sloc[4];
    #pragma unroll
    for (int r = 0; r < 4; r++) { mloc[r] = -INFINITY; sloc[r] = 0.f; }

    for (int ct = 0; ct < Tk; ct += 64) {
        __syncthreads();
        {
            int cc = tid;
            #pragma unroll
            for (int rep = 0; rep < 2; rep++, cc += 512) {
                int row = cc >> 4;
                int off = (cc & 15) * 8;
                int tcol = k + ct + row;
                *(uint4*)&Zt[row][off] = *(const uint4*)(zb + (size_t)tcol * P_ + off);
            }
        }
        __syncthreads();
        f32x4 acc[4] = {};
        #pragma unroll
        for (int k0 = 0; k0 < 4; k0++) {
            bf16x8 af = *(const bf16x8*)(&Pst[w * 16 + col][k0 * 32 + quad * 8]);
            #pragma unroll
            for (int nt = 0; nt < 4; nt++) {
                bf16x8 bf = *(const bf16x8*)(&Zt[nt * 16 + col][k0 * 32 + quad * 8]);
                acc[nt] = __builtin_amdgcn_mfma_f32_16x16x32_bf16(af, bf, acc[nt], 0, 0, 0);
            }
        }
        #pragma unroll
        for (int r = 0; r < 4; r++) {
            float l[4];
            float tmax = -INFINITY;
            #pragma unroll
            for (int nt = 0; nt < 4; nt++) {
                bool valid = (ct + nt * 16 + col) < Tk;
                l[nt] = valid ? acc[nt][r] * INV_TEMP : -INFINITY;
                tmax = fmaxf(tmax, l[nt]);
            }
            float mnew = fmaxf(mloc[r], tmax);
            float e = __expf(l[0] - mnew) + __expf(l[1] - mnew)
                    + __expf(l[2] - mnew) + __expf(l[3] - mnew);
            sloc[r] = sloc[r] * __expf(mloc[r] - mnew) + e;
            mloc[r] = mnew;
        }
    }
    #pragma unroll
    for (int r = 0; r < 4; r++) {
        #pragma unroll
        for (int o = 1; o < 16; o <<= 1) {
            float mo = __shfl_xor(mloc[r], o, 64);
            float so = __shfl_xor(sloc[r], o, 64);
            float mn = fmaxf(mloc[r], mo);
            sloc[r] = sloc[r] * __expf(mloc[r] - mn) + so * __expf(mo - mn);
            mloc[r] = mn;
        }
    }
    float tkinv = INV_TEMP / (float)Tk;
    float scale = 1.0f / ((float)K_ * (float)B_ * (float)Tk);
    float bs = 0.f;
    #pragma unroll
    for (int r = 0; r < 4; r++) {
        int row = w * 16 + quad * 4 + r;
        BF8 pv;
        pv.v = *(const bf16x8*)(&Pst[row][col * 8]);
        float d = 0.f;
        #pragma unroll
        for (int m = 0; m < 8; m++) d = fmaf(bf2f(pv.e[m]), sS[col * 8 + m], d);
        #pragma unroll
        for (int o = 1; o < 16; o <<= 1) d += __shfl_xor(d, o, 64);
        int gr = t0 + row;
        if (gr < Tk) bs += mloc[r] + __logf(sloc[r]) - d * tkinv;
    }
    if (col != 0) bs = 0.f;
    bs = wave_sum(bs);
    if (lane == 0) red[w] = bs;
    __syncthreads();
    if (tid == 0) {
        float tot = 0.f;
        #pragma unroll
        for (int i = 0; i < 8; i++) tot += red[i];
        atomicAdd(&accum[(blockIdx.x * 809 + b * 67 + blockIdx.z * 131) & 1023],
                  tot * scale);
    }
#endif
}

__global__ void finalize(const float* __restrict__ accum, float* __restrict__ out) {
    int tid = threadIdx.x;
    __shared__ float red[4];
    float v = 0.f;
    for (int i = tid; i < 1024; i += 256) v += accum[i];
    float sres = wave_sum(v);
    if ((tid & 63) == 0) red[tid >> 6] = sres;
    __syncthreads();
    if (tid == 0) out[0] = red[0] + red[1] + red[2] + red[3];
}

// ---------------- launch -----------------------------------------------------
extern "C" void kernel_launch(void* const* d_in, const int* in_sizes, int n_in,
                              void* d_out, int out_size, void* d_ws, size_t ws_size,
                              hipStream_t stream) {
    const float* x      = (const float*)d_in[0];
    const float* W_enc  = (const float*)d_in[1];
    const float* b_enc  = (const float*)d_in[2];
    const float* W_proj = (const float*)d_in[3];
    const float* b_proj = (const float*)d_in[4];
    const float* Wi     = (const float*)d_in[5];
    const float* bi     = (const float*)d_in[6];
    const float* Wh     = (const float*)d_in[7];
    const float* bhn    = (const float*)d_in[8];
    const float* Wp     = (const float*)d_in[9];
    const float* bp     = (const float*)d_in[10];
    float* out = (float*)d_out;

    // layout (float offsets)
    float* ws    = (float*)d_ws;
    float* bc    = ws;                          // 128
    float* accum = bc + 128;                    // 1024 -> end 1152
    u16* Wct     = (u16*)(ws + 1152);           // 16384 fl -> end 17536
    u16* Wit     = (u16*)(ws + 17536);          // 49152 fl -> end 66688
    u16* Wpt     = (u16*)(ws + 66688);          // 196608 fl -> end 263296
    uint2* Wq    = (uint2*)(ws + 263296);       // 24576 i64 = 49152 fl -> end 312448
    u16* zh      = (u16*)(ws + 312448);         // 2097152 fl -> end 2409600
    float* zsum  = ws + 2409600;                // 8192 fl (doubles as zh slack) -> end 2417792
    u16* gi      = (u16*)(ws + 2417792);        // 12582912 fl -> end 15000704
    u16* ch      = (u16*)(ws + 15000704);       // 4194304 fl -> end 19195008 (~77 MB)

    const int MT = B_ * T_;                     // 32768

    setup_conv<<<705, 256, 0, stream>>>(Wh, Wi, Wit, Wp, Wpt,
                                        W_enc, b_enc, W_proj, b_proj, Wct, bc, accum,
                                        Wq);
    // zh = bf16(x @ Wct^T + bc)   (M=32768, N=128, K=256; A converted in-reg)
    gemm_mfma_f32a<<<dim3(1, MT / 64), 256, 0, stream>>>(x, Wct, bc, zh, P_, F_);
    // gi = bf16(zh @ Wit^T + bi)  (M=32768, N=768, K=128)
    gemm_mfma<<<dim3(6, MT / 64), 256, 0, stream>>>(zh, Wit, bi, gi, 3 * H_, P_);
    // fp8-MFMA GRU (8 blocks) + zsum (64 blocks) — launched UNCONDITIONALLY
    // (r15 bug: host-side __has_builtin is always false -> fallback ran)
    gru_zsum_mfma<<<8 + B_, 512, 0, stream>>>(gi, (const long long*)Wq, bhn, ch, zh, zsum);
    // fused pred-GEMM + flash loss (MFMA), 128-row tiles, LDS-staged zh
    loss_fused<<<dim3(4, B_, K_), 512, 0, stream>>>(ch, Wpt, bp, zh, zsum, accum);
    finalize<<<1, 256, 0, stream>>>(accum, out);
}

// Round 17
// 1106.045 us; speedup vs baseline: 1.2590x; 1.2590x over previous
//
#include <hip/hip_runtime.h>
#include <hip/hip_bf16.h>
#include <math.h>

#define B_   64
#define T_   512
#define F_   256
#define ENC_ 256
#define P_   128
#define H_   256
#define K_   12
#define INV_TEMP 10.0f

typedef unsigned short u16;
typedef _Float16 half2v __attribute__((ext_vector_type(2)));
union U2H { unsigned int u; half2v h; };
typedef __attribute__((ext_vector_type(8))) short bf16x8;   // 8 bf16 = 4 VGPRs
typedef __attribute__((ext_vector_type(4))) float f32x4;    // MFMA C/D
union BF8 { bf16x8 v; u16 e[8]; };

// ---------------- helpers ----------------------------------------------------
__device__ __forceinline__ float dot2f16(unsigned int a, unsigned int b, float c) {
    U2H ua; ua.u = a; U2H ub; ub.u = b;
#if __has_builtin(__builtin_amdgcn_fdot2)
    return __builtin_amdgcn_fdot2(ua.h, ub.h, c, false);
#else
    return fmaf((float)ua.h.x, (float)ub.h.x, fmaf((float)ua.h.y, (float)ub.h.y, c));
#endif
}
__device__ __forceinline__ float rcpf(float x) {
#if __has_builtin(__builtin_amdgcn_rcpf)
    return __builtin_amdgcn_rcpf(x);
#else
    return 1.f / x;
#endif
}
__device__ __forceinline__ u16 f2bf(float f) {   // RNE
    unsigned int u = __float_as_uint(f);
    unsigned int r = (u + 0x7fffu + ((u >> 16) & 1u)) >> 16;
    return (u16)r;
}
__device__ __forceinline__ float bf2f(u16 v) {
    return __uint_as_float(((unsigned int)v) << 16);
}
__device__ __forceinline__ float bflo(unsigned int u) { return __uint_as_float(u << 16); }
__device__ __forceinline__ float bfhi(unsigned int u) { return __uint_as_float(u & 0xffff0000u); }
__device__ __forceinline__ float wave_sum(float v) {
    #pragma unroll
    for (int o = 32; o > 0; o >>= 1) v += __shfl_down(v, o, 64);
    return v;
}

// ---------------- merged setup: weight conversions + fold + accum/cnt zero ---
// 0..191: Wh -> packed f16 Whh; 192..287: Wi -> Wit bf16 (transposed);
// 288..671: Wp -> Wpt bf16 (transposed); 672..800: fold (Wct, bc, accum, cnt)
__global__ __launch_bounds__(256) void setup_conv(const float* __restrict__ Wh,
                                                  uint2* __restrict__ Whh,
                                                  const float* __restrict__ Wi,
                                                  u16* __restrict__ Wit,
                                                  const float* __restrict__ Wp,
                                                  u16* __restrict__ Wpt,
                                                  const float* __restrict__ We,
                                                  const float* __restrict__ be,
                                                  const float* __restrict__ Wpj,
                                                  const float* __restrict__ bpj,
                                                  u16* __restrict__ Wct,
                                                  float* __restrict__ bc,
                                                  float* __restrict__ accum,
                                                  unsigned* __restrict__ cnt) {
    int bid = blockIdx.x;
    if (bid < 192) {
        int idx = bid * 256 + threadIdx.x;        // 49152 total
        int i4 = idx / 768, j = idx % 768;
        U2H lo, hi;
        lo.h.x = (_Float16)Wh[(size_t)(4 * i4 + 0) * 768 + j];
        lo.h.y = (_Float16)Wh[(size_t)(4 * i4 + 1) * 768 + j];
        hi.h.x = (_Float16)Wh[(size_t)(4 * i4 + 2) * 768 + j];
        hi.h.y = (_Float16)Wh[(size_t)(4 * i4 + 3) * 768 + j];
        Whh[idx] = make_uint2(lo.u, hi.u);
    } else if (bid < 288) {
        __shared__ float tile[32][33];
        int b2 = bid - 192;                       // 0..95
        int n0 = (b2 % 24) * 32, k0 = (b2 / 24) * 32;
        int tx = threadIdx.x & 31, ty = threadIdx.x >> 5;
        #pragma unroll
        for (int i = 0; i < 32; i += 8)
            tile[ty + i][tx] = Wi[(size_t)(k0 + ty + i) * 768 + n0 + tx];
        __syncthreads();
        #pragma unroll
        for (int i = 0; i < 32; i += 8)
            Wit[(size_t)(n0 + ty + i) * 128 + k0 + tx] = f2bf(tile[tx][ty + i]);
    } else if (bid < 672) {
        __shared__ float tile2[32][33];
        int b3 = bid - 288;                       // 0..383
        int kq = b3 / 32, rem = b3 % 32;
        int h0 = (rem % 8) * 32, p0 = (rem / 8) * 32;
        int tx = threadIdx.x & 31, ty = threadIdx.x >> 5;
        #pragma unroll
        for (int i = 0; i < 32; i += 8)
            tile2[ty + i][tx] = Wp[(size_t)kq * H_ * P_ + (size_t)(h0 + ty + i) * P_ + p0 + tx];
        __syncthreads();
        #pragma unroll
        for (int i = 0; i < 32; i += 8)
            Wpt[(size_t)kq * P_ * H_ + (size_t)(p0 + ty + i) * H_ + h0 + tx] = f2bf(tile2[tx][ty + i]);
    } else {
        // fold: f = 2*(bid-672) + (tid>>7); p = tid&127
        int f = (bid - 672) * 2 + (threadIdx.x >> 7);
        int p = threadIdx.x & 127;
        if (f < F_) {
            float a = 0.f;
            for (int e = 0; e < ENC_; e++) a = fmaf(We[f * ENC_ + e], Wpj[e * P_ + p], a);
            Wct[(size_t)p * F_ + f] = f2bf(a);
        } else if (f == F_) {
            float a = bpj[p];
            for (int e = 0; e < ENC_; e++) a = fmaf(be[e], Wpj[e * P_ + p], a);
            bc[p] = a;
        } else {
            #pragma unroll
            for (int i = 0; i < 8; i++) accum[p * 8 + i] = 0.f;
            if (p == 0) cnt[0] = 0u;
        }
    }
}

// ---------------- MFMA GEMM, A = fp32 (converted in-register) ----------------
__global__ __launch_bounds__(256) void gemm_mfma_f32a(const float* __restrict__ A,
                                                      const u16* __restrict__ Bt,
                                                      const float* __restrict__ bias,
                                                      u16* __restrict__ Ch,
                                                      int N, int K) {
    int tid  = threadIdx.x;
    int w    = tid >> 6;
    int lane = tid & 63;
    int col  = lane & 15;
    int quad = lane >> 4;
    int bm = blockIdx.y * 64, bn = blockIdx.x * 128;

    f32x4 acc[8] = {};
    const float* arow = A + (size_t)(bm + w * 16 + col) * K;
    #pragma unroll
    for (int k0 = 0; k0 < K; k0 += 32) {
        float4 v0 = *(const float4*)(arow + k0 + quad * 8);
        float4 v1 = *(const float4*)(arow + k0 + quad * 8 + 4);
        BF8 af;
        af.e[0] = f2bf(v0.x); af.e[1] = f2bf(v0.y); af.e[2] = f2bf(v0.z); af.e[3] = f2bf(v0.w);
        af.e[4] = f2bf(v1.x); af.e[5] = f2bf(v1.y); af.e[6] = f2bf(v1.z); af.e[7] = f2bf(v1.w);
        #pragma unroll
        for (int nt = 0; nt < 8; nt++) {
            bf16x8 bf = *(const bf16x8*)(Bt + (size_t)(bn + nt * 16 + col) * K + k0 + quad * 8);
            acc[nt] = __builtin_amdgcn_mfma_f32_16x16x32_bf16(af.v, bf, acc[nt], 0, 0, 0);
        }
    }
    #pragma unroll
    for (int nt = 0; nt < 8; nt++) {
        int gn = bn + nt * 16 + col;
        float bv = bias[gn];
        #pragma unroll
        for (int r = 0; r < 4; r++) {
            int gm = bm + w * 16 + quad * 4 + r;
            Ch[(size_t)gm * N + gn] = f2bf(acc[nt][r] + bv);
        }
    }
}

// ---------------- MFMA GEMM, A = bf16, C = bf16 ------------------------------
__global__ __launch_bounds__(256) void gemm_mfma(const u16* __restrict__ A,
                                                 const u16* __restrict__ Bt,
                                                 const float* __restrict__ bias,
                                                 u16* __restrict__ Ch,
                                                 int N, int K) {
    int tid  = threadIdx.x;
    int w    = tid >> 6;
    int lane = tid & 63;
    int col  = lane & 15;
    int quad = lane >> 4;
    int bm = blockIdx.y * 64, bn = blockIdx.x * 128;

    f32x4 acc[8] = {};
    const u16* arow = A + (size_t)(bm + w * 16 + col) * K;
    #pragma unroll
    for (int k0 = 0; k0 < K; k0 += 32) {
        bf16x8 af = *(const bf16x8*)(arow + k0 + quad * 8);
        #pragma unroll
        for (int nt = 0; nt < 8; nt++) {
            bf16x8 bf = *(const bf16x8*)(Bt + (size_t)(bn + nt * 16 + col) * K + k0 + quad * 8);
            acc[nt] = __builtin_amdgcn_mfma_f32_16x16x32_bf16(af, bf, acc[nt], 0, 0, 0);
        }
    }
    #pragma unroll
    for (int nt = 0; nt < 8; nt++) {
        int gn = bn + nt * 16 + col;
        float bv = bias[gn];
        #pragma unroll
        for (int r = 0; r < 4; r++) {
            int gm = bm + w * 16 + quad * 4 + r;
            Ch[(size_t)gm * N + gn] = f2bf(acc[nt][r] + bv);
        }
    }
}

// ---------------- GRU scan (blocks 0..63, r10 structure — measured optimum) --
// + zsum (blocks 64..127, rides CUs the 64-block GRU leaves idle)
__global__ __attribute__((amdgpu_flat_work_group_size(512, 512), amdgpu_waves_per_eu(2, 2)))
void gru_zsum_kernel(const u16* __restrict__ gi,
                     const uint2* __restrict__ Whh,
                     const float* __restrict__ bhn,
                     u16* __restrict__ ch,
                     const u16* __restrict__ zh,
                     float* __restrict__ zsum) {
    __shared__ __align__(16) char shraw[8704];
    int tid = threadIdx.x;          // 0..511

    if (blockIdx.x >= B_) {
        // ---- zsum[b][p] = sum_{t=1..T-1} z[b][t][p], 16-way t-split ---------
        float (*part)[128] = (float(*)[128])shraw;   // 8192 B
        int b   = blockIdx.x - B_;
        int pg  = tid & 31;
        int g   = tid >> 5;
        const u16* zb = zh + (size_t)b * T_ * P_;
        float s0 = 0.f, s1 = 0.f, s2 = 0.f, s3 = 0.f;
        for (int t = 1 + g; t < T_; t += 16) {
            uint2 v = *(const uint2*)(zb + (size_t)t * P_ + pg * 4);
            s0 += bflo(v.x); s1 += bfhi(v.x);
            s2 += bflo(v.y); s3 += bfhi(v.y);
        }
        part[g][pg * 4 + 0] = s0; part[g][pg * 4 + 1] = s1;
        part[g][pg * 4 + 2] = s2; part[g][pg * 4 + 3] = s3;
        __syncthreads();
        if (tid < 128) {
            float s = 0.f;
            #pragma unroll
            for (int g2 = 0; g2 < 16; g2++) s += part[g2][tid];
            zsum[(size_t)b * P_ + tid] = s;
        }
        return;
    }

    // ---- GRU: thread (j, half) owns gate cols j/j+256/j+512 for h-rows
    // [128*half, ...+128). 192 dw f16 weights/thread at 2 waves/SIMD. ---------
    _Float16* hbuf = (_Float16*)shraw;                       // 512 B
    float4 (*ps)[256] = (float4(*)[256])(shraw + 512);       // 8192 B
    int b    = blockIdx.x;
    int j    = tid & 255;
    int half = tid >> 8;

    uint2 wR[32], wZ[32], wN[32];
    {
        const uint2* base = Whh + (size_t)(half * 32) * 768;
        const uint2* cR = base + j;
        const uint2* cZ = base + 256 + j;
        const uint2* cN = base + 512 + j;
        #pragma unroll
        for (int i = 0; i < 32; i++) {
            wR[i] = cR[(size_t)i * 768];
            wZ[i] = cZ[(size_t)i * 768];
            wN[i] = cN[(size_t)i * 768];
        }
        #pragma unroll
        for (int i = 0; i < 32; i++) {
            asm volatile("" : "+v"(wR[i].x), "+v"(wR[i].y));
            asm volatile("" : "+v"(wZ[i].x), "+v"(wZ[i].y));
            asm volatile("" : "+v"(wN[i].x), "+v"(wN[i].y));
        }
    }
    if (tid < H_) hbuf[tid] = (_Float16)0.f;
    float bh = bhn[j];
    float hloc = 0.f;

    const u16* gib = gi + (size_t)b * T_ * 768;
    u16* cb = ch + (size_t)b * T_ * H_;
    float ir = 0.f, iz = 0.f, inn = 0.f;
    if (tid < 256) { ir = bf2f(gib[j]); iz = bf2f(gib[256 + j]); inn = bf2f(gib[512 + j]); }
    __syncthreads();

    const uint2* hw = (const uint2*)hbuf;
    #pragma unroll 1
    for (int t = 0; t < T_; t++) {
        float nir = 0.f, niz = 0.f, ninn = 0.f;
        if (tid < 256) {
            int tn = (t + 1 < T_) ? t + 1 : t;
            const u16* gtn = gib + (size_t)tn * 768;
            nir = bf2f(gtn[j]); niz = bf2f(gtn[256 + j]); ninn = bf2f(gtn[512 + j]);
        }
        float ar0 = 0.f, ar1 = 0.f, az0 = 0.f, az1 = 0.f, an0 = 0.f, an1 = 0.f;
        #pragma unroll
        for (int i = 0; i < 32; i++) {
            uint2 hv = hw[half * 32 + i];
            ar0 = dot2f16(hv.x, wR[i].x, ar0);
            ar1 = dot2f16(hv.y, wR[i].y, ar1);
            az0 = dot2f16(hv.x, wZ[i].x, az0);
            az1 = dot2f16(hv.y, wZ[i].y, az1);
            an0 = dot2f16(hv.x, wN[i].x, an0);
            an1 = dot2f16(hv.y, wN[i].y, an1);
        }
        ps[half][j] = make_float4(ar0 + ar1, az0 + az1, an0 + an1, 0.f);
        __syncthreads();
        if (tid < 256) {
            float4 p0 = ps[0][j], p1 = ps[1][j];
            float ar = p0.x + p1.x;
            float az = p0.y + p1.y;
            float an = p0.z + p1.z;
            float r   = rcpf(1.f + __expf(-(ir + ar)));
            float zg  = rcpf(1.f + __expf(-(iz + az)));
            float xn  = inn + r * (an + bh);
            float n   = fmaf(2.f, rcpf(1.f + __expf(-2.f * xn)), -1.f);
            hloc = (1.f - zg) * n + zg * hloc;
            cb[(size_t)t * H_ + j] = f2bf(hloc);
            hbuf[j] = (_Float16)hloc;
        }
        ir = nir; iz = niz; inn = ninn;
        __syncthreads();
    }
}

// ---------------- fused loss + inline finalize -------------------------------
// 128-row tiles, zh tiles staged in LDS. Last of the 3072 blocks (device-scope
// completion counter) reduces accum and writes out — kills the finalize launch.
__global__ __launch_bounds__(512) void loss_fused(const u16* __restrict__ ch,
                                                  const u16* __restrict__ Wpt,
                                                  const float* __restrict__ bp,
                                                  const u16* __restrict__ zh,
                                                  const float* __restrict__ zsum,
                                                  float* __restrict__ accum,
                                                  unsigned* __restrict__ cnt,
                                                  float* __restrict__ out) {
    __shared__ u16 Pst[128][136];
    __shared__ u16 Zt[64][136];
    __shared__ float sS[128];
    __shared__ float red[8];
    __shared__ int lastFlag;
    int k  = blockIdx.z + 1;
    int b  = blockIdx.y;
    int t0 = blockIdx.x * 128;
    int Tk = T_ - k;
    int tid  = threadIdx.x;
    int w    = tid >> 6;
    int lane = tid & 63;
    int col  = lane & 15;
    int quad = lane >> 4;
    const u16* zb = zh + (size_t)b * T_ * P_;

    // S_bk = zsum_b - sum_{t=1}^{k-1} z[t]
    if (tid < 128) {
        float s = zsum[(size_t)b * P_ + tid];
        for (int t = 1; t < k; t++) s -= bf2f(zb[(size_t)t * P_ + tid]);
        sS[tid] = s;
    }

    // ---- phase 1: Pst = bf16(ch-tile @ Wp[k] + bp[k]) -----------------------
    {
        f32x4 acc[8] = {};
        const u16* arow = ch + ((size_t)b * T_ + t0 + w * 16 + col) * H_;
        const u16* wk   = Wpt + (size_t)(k - 1) * P_ * H_;
        #pragma unroll
        for (int k0 = 0; k0 < 8; k0++) {
            bf16x8 af = *(const bf16x8*)(arow + k0 * 32 + quad * 8);
            #pragma unroll
            for (int nt = 0; nt < 8; nt++) {
                bf16x8 bf = *(const bf16x8*)(wk + (size_t)(nt * 16 + col) * H_ + k0 * 32 + quad * 8);
                acc[nt] = __builtin_amdgcn_mfma_f32_16x16x32_bf16(af, bf, acc[nt], 0, 0, 0);
            }
        }
        #pragma unroll
        for (int nt = 0; nt < 8; nt++) {
            float bias = bp[(size_t)(k - 1) * P_ + nt * 16 + col];
            #pragma unroll
            for (int r = 0; r < 4; r++)
                Pst[w * 16 + quad * 4 + r][nt * 16 + col] = f2bf(acc[nt][r] + bias);
        }
    }
    __syncthreads();

    // ---- phase 2: flash LSE over LDS-staged zh tiles ------------------------
    float mloc[4], sloc[4];
    #pragma unroll
    for (int r = 0; r < 4; r++) { mloc[r] = -INFINITY; sloc[r] = 0.f; }

    for (int ct = 0; ct < Tk; ct += 64) {
        __syncthreads();             // Zt free (prev tile's MFMAs done)
        {
            // 64 rows x 256 B = 16 KB contiguous; 512 thr x 2 x 16 B, coalesced
            int cc = tid;
            #pragma unroll
            for (int rep = 0; rep < 2; rep++, cc += 512) {
                int row = cc >> 4;
                int off = (cc & 15) * 8;
                int tcol = k + ct + row;     // may over-read into slack (masked)
                *(uint4*)&Zt[row][off] = *(const uint4*)(zb + (size_t)tcol * P_ + off);
            }
        }
        __syncthreads();
        f32x4 acc[4] = {};
        #pragma unroll
        for (int k0 = 0; k0 < 4; k0++) {
            bf16x8 af = *(const bf16x8*)(&Pst[w * 16 + col][k0 * 32 + quad * 8]);
            #pragma unroll
            for (int nt = 0; nt < 4; nt++) {
                bf16x8 bf = *(const bf16x8*)(&Zt[nt * 16 + col][k0 * 32 + quad * 8]);
                acc[nt] = __builtin_amdgcn_mfma_f32_16x16x32_bf16(af, bf, acc[nt], 0, 0, 0);
            }
        }
        #pragma unroll
        for (int r = 0; r < 4; r++) {
            float l[4];
            float tmax = -INFINITY;
            #pragma unroll
            for (int nt = 0; nt < 4; nt++) {
                bool valid = (ct + nt * 16 + col) < Tk;
                l[nt] = valid ? acc[nt][r] * INV_TEMP : -INFINITY;
                tmax = fmaxf(tmax, l[nt]);
            }
            float mnew = fmaxf(mloc[r], tmax);
            float e = __expf(l[0] - mnew) + __expf(l[1] - mnew)
                    + __expf(l[2] - mnew) + __expf(l[3] - mnew);
            sloc[r] = sloc[r] * __expf(mloc[r] - mnew) + e;
            mloc[r] = mnew;
        }
    }
    #pragma unroll
    for (int r = 0; r < 4; r++) {
        #pragma unroll
        for (int o = 1; o < 16; o <<= 1) {
            float mo = __shfl_xor(mloc[r], o, 64);
            float so = __shfl_xor(sloc[r], o, 64);
            float mn = fmaxf(mloc[r], mo);
            sloc[r] = sloc[r] * __expf(mloc[r] - mn) + so * __expf(mo - mn);
            mloc[r] = mn;
        }
    }
    float tkinv = INV_TEMP / (float)Tk;
    float scale = 1.0f / ((float)K_ * (float)B_ * (float)Tk);
    float bs = 0.f;
    #pragma unroll
    for (int r = 0; r < 4; r++) {
        int row = w * 16 + quad * 4 + r;
        BF8 pv;
        pv.v = *(const bf16x8*)(&Pst[row][col * 8]);
        float d = 0.f;
        #pragma unroll
        for (int m = 0; m < 8; m++) d = fmaf(bf2f(pv.e[m]), sS[col * 8 + m], d);
        #pragma unroll
        for (int o = 1; o < 16; o <<= 1) d += __shfl_xor(d, o, 64);
        int gr = t0 + row;
        if (gr < Tk) bs += mloc[r] + __logf(sloc[r]) - d * tkinv;
    }
    if (col != 0) bs = 0.f;
    bs = wave_sum(bs);
    if (lane == 0) red[w] = bs;
    __syncthreads();
    if (tid == 0) {
        float tot = 0.f;
        #pragma unroll
        for (int i = 0; i < 8; i++) tot += red[i];
        atomicAdd(&accum[(blockIdx.x * 809 + b * 67 + blockIdx.z * 131) & 1023],
                  tot * scale);
        __threadfence();             // make this block's accum add visible
        unsigned done = atomicAdd(cnt, 1u);
        lastFlag = (done == 4 * B_ * K_ - 1);   // 3072 blocks total
    }
    __syncthreads();
    if (lastFlag) {
        // last block: reduce accum[1024] -> out (atomics are device-coherent)
        float v = accum[tid] + accum[tid + 512];
        v = wave_sum(v);
        if (lane == 0) red[w] = v;
        __syncthreads();
        if (tid == 0) {
            float tot = 0.f;
            #pragma unroll
            for (int i = 0; i < 8; i++) tot += red[i];
            out[0] = tot;
        }
    }
}

// ---------------- launch -----------------------------------------------------
extern "C" void kernel_launch(void* const* d_in, const int* in_sizes, int n_in,
                              void* d_out, int out_size, void* d_ws, size_t ws_size,
                              hipStream_t stream) {
    const float* x      = (const float*)d_in[0];
    const float* W_enc  = (const float*)d_in[1];
    const float* b_enc  = (const float*)d_in[2];
    const float* W_proj = (const float*)d_in[3];
    const float* b_proj = (const float*)d_in[4];
    const float* Wi     = (const float*)d_in[5];
    const float* bi     = (const float*)d_in[6];
    const float* Wh     = (const float*)d_in[7];
    const float* bhn    = (const float*)d_in[8];
    const float* Wp     = (const float*)d_in[9];
    const float* bp     = (const float*)d_in[10];
    float* out = (float*)d_out;

    // layout (float offsets)
    float* ws     = (float*)d_ws;
    float* bc     = ws;                          // 128
    float* accum  = bc + 128;                    // 1024 -> end 1152
    unsigned* cnt = (unsigned*)(ws + 1152);      // 4 fl -> end 1156
    uint2* Whh    = (uint2*)(ws + 1156);         // 98304 fl -> end 99460
    u16* Wct      = (u16*)(ws + 99460);          // 16384 fl -> end 115844
    u16* Wit      = (u16*)(ws + 115844);         // 49152 fl -> end 164996
    u16* Wpt      = (u16*)(ws + 164996);         // 196608 fl -> end 361604
    u16* zh       = (u16*)(ws + 361604);         // 2097152 fl -> end 2458756
    float* zsum   = ws + 2458756;                // 8192 fl (doubles as zh slack) -> end 2466948
    u16* gi       = (u16*)(ws + 2466948);        // 12582912 fl -> end 15049860
    u16* ch       = (u16*)(ws + 15049860);       // 4194304 fl -> end 19244164 (~77 MB)

    const int MT = B_ * T_;                      // 32768

    // merged setup: weight conversions + fold + accum/counter zero (801 blocks)
    setup_conv<<<801, 256, 0, stream>>>(Wh, Whh, Wi, Wit, Wp, Wpt,
                                        W_enc, b_enc, W_proj, b_proj, Wct, bc, accum, cnt);
    // zh = bf16(x @ Wct^T + bc)   (M=32768, N=128, K=256; A converted in-reg)
    gemm_mfma_f32a<<<dim3(1, MT / 64), 256, 0, stream>>>(x, Wct, bc, zh, P_, F_);
    // gi = bf16(zh @ Wit^T + bi)  (M=32768, N=768, K=128)
    gemm_mfma<<<dim3(6, MT / 64), 256, 0, stream>>>(zh, Wit, bi, gi, 3 * H_, P_);
    // GRU scan -> ch (blocks 0..63, dot2 — measured optimum) + zsum (64..127)
    gru_zsum_kernel<<<2 * B_, 512, 0, stream>>>(gi, Whh, bhn, ch, zh, zsum);
    // fused pred-GEMM + flash loss (MFMA) + inline finalize (last block)
    loss_fused<<<dim3(4, B_, K_), 512, 0, stream>>>(ch, Wpt, bp, zh, zsum, accum, cnt, out);
}

// Round 18
// 1052.982 us; speedup vs baseline: 1.3225x; 1.0504x over previous
//
#include <hip/hip_runtime.h>
#include <hip/hip_bf16.h>
#include <math.h>

#define B_   64
#define T_   512
#define F_   256
#define ENC_ 256
#define P_   128
#define H_   256
#define K_   12
#define INV_TEMP 10.0f

typedef unsigned short u16;
typedef _Float16 half2v __attribute__((ext_vector_type(2)));
union U2H { unsigned int u; half2v h; };
typedef __attribute__((ext_vector_type(8))) short bf16x8;   // 8 bf16 = 4 VGPRs
typedef __attribute__((ext_vector_type(4))) float f32x4;    // MFMA C/D
union BF8 { bf16x8 v; u16 e[8]; };

// ---------------- helpers ----------------------------------------------------
__device__ __forceinline__ float dot2f16(unsigned int a, unsigned int b, float c) {
    U2H ua; ua.u = a; U2H ub; ub.u = b;
#if __has_builtin(__builtin_amdgcn_fdot2)
    return __builtin_amdgcn_fdot2(ua.h, ub.h, c, false);
#else
    return fmaf((float)ua.h.x, (float)ub.h.x, fmaf((float)ua.h.y, (float)ub.h.y, c));
#endif
}
__device__ __forceinline__ float rcpf(float x) {
#if __has_builtin(__builtin_amdgcn_rcpf)
    return __builtin_amdgcn_rcpf(x);
#else
    return 1.f / x;
#endif
}
__device__ __forceinline__ u16 f2bf(float f) {   // RNE
    unsigned int u = __float_as_uint(f);
    unsigned int r = (u + 0x7fffu + ((u >> 16) & 1u)) >> 16;
    return (u16)r;
}
__device__ __forceinline__ float bf2f(u16 v) {
    return __uint_as_float(((unsigned int)v) << 16);
}
__device__ __forceinline__ float bflo(unsigned int u) { return __uint_as_float(u << 16); }
__device__ __forceinline__ float bfhi(unsigned int u) { return __uint_as_float(u & 0xffff0000u); }
__device__ __forceinline__ float wave_sum(float v) {
    #pragma unroll
    for (int o = 32; o > 0; o >>= 1) v += __shfl_down(v, o, 64);
    return v;
}

// ---------------- merged setup: weight conversions + fold + accum zero -------
// blocks 0..191: Wh -> packed f16 Whh; 192..287: Wi -> Wit bf16 (transposed);
// 288..671: Wp -> Wpt bf16 (transposed); 672..800: fold (Wct, bc, accum=0)
__global__ __launch_bounds__(256) void setup_conv(const float* __restrict__ Wh,
                                                  uint2* __restrict__ Whh,
                                                  const float* __restrict__ Wi,
                                                  u16* __restrict__ Wit,
                                                  const float* __restrict__ Wp,
                                                  u16* __restrict__ Wpt,
                                                  const float* __restrict__ We,
                                                  const float* __restrict__ be,
                                                  const float* __restrict__ Wpj,
                                                  const float* __restrict__ bpj,
                                                  u16* __restrict__ Wct,
                                                  float* __restrict__ bc,
                                                  float* __restrict__ accum) {
    int bid = blockIdx.x;
    if (bid < 192) {
        int idx = bid * 256 + threadIdx.x;        // 49152 total
        int i4 = idx / 768, j = idx % 768;
        U2H lo, hi;
        lo.h.x = (_Float16)Wh[(size_t)(4 * i4 + 0) * 768 + j];
        lo.h.y = (_Float16)Wh[(size_t)(4 * i4 + 1) * 768 + j];
        hi.h.x = (_Float16)Wh[(size_t)(4 * i4 + 2) * 768 + j];
        hi.h.y = (_Float16)Wh[(size_t)(4 * i4 + 3) * 768 + j];
        Whh[idx] = make_uint2(lo.u, hi.u);
    } else if (bid < 288) {
        __shared__ float tile[32][33];
        int b2 = bid - 192;                       // 0..95
        int n0 = (b2 % 24) * 32, k0 = (b2 / 24) * 32;
        int tx = threadIdx.x & 31, ty = threadIdx.x >> 5;
        #pragma unroll
        for (int i = 0; i < 32; i += 8)
            tile[ty + i][tx] = Wi[(size_t)(k0 + ty + i) * 768 + n0 + tx];
        __syncthreads();
        #pragma unroll
        for (int i = 0; i < 32; i += 8)
            Wit[(size_t)(n0 + ty + i) * 128 + k0 + tx] = f2bf(tile[tx][ty + i]);
    } else if (bid < 672) {
        __shared__ float tile2[32][33];
        int b3 = bid - 288;                       // 0..383
        int kq = b3 / 32, rem = b3 % 32;
        int h0 = (rem % 8) * 32, p0 = (rem / 8) * 32;
        int tx = threadIdx.x & 31, ty = threadIdx.x >> 5;
        #pragma unroll
        for (int i = 0; i < 32; i += 8)
            tile2[ty + i][tx] = Wp[(size_t)kq * H_ * P_ + (size_t)(h0 + ty + i) * P_ + p0 + tx];
        __syncthreads();
        #pragma unroll
        for (int i = 0; i < 32; i += 8)
            Wpt[(size_t)kq * P_ * H_ + (size_t)(p0 + ty + i) * H_ + h0 + tx] = f2bf(tile2[tx][ty + i]);
    } else {
        // fold: f = 2*(bid-672) + (tid>>7); p = tid&127
        int f = (bid - 672) * 2 + (threadIdx.x >> 7);
        int p = threadIdx.x & 127;
        if (f < F_) {
            float a = 0.f;
            for (int e = 0; e < ENC_; e++) a = fmaf(We[f * ENC_ + e], Wpj[e * P_ + p], a);
            Wct[(size_t)p * F_ + f] = f2bf(a);
        } else if (f == F_) {
            float a = bpj[p];
            for (int e = 0; e < ENC_; e++) a = fmaf(be[e], Wpj[e * P_ + p], a);
            bc[p] = a;
        } else {
            #pragma unroll
            for (int i = 0; i < 8; i++) accum[p * 8 + i] = 0.f;
        }
    }
}

// ---------------- MFMA GEMM, A = fp32 (converted in-register) ----------------
__global__ __launch_bounds__(256) void gemm_mfma_f32a(const float* __restrict__ A,
                                                      const u16* __restrict__ Bt,
                                                      const float* __restrict__ bias,
                                                      u16* __restrict__ Ch,
                                                      int N, int K) {
    int tid  = threadIdx.x;
    int w    = tid >> 6;
    int lane = tid & 63;
    int col  = lane & 15;
    int quad = lane >> 4;
    int bm = blockIdx.y * 64, bn = blockIdx.x * 128;

    f32x4 acc[8] = {};
    const float* arow = A + (size_t)(bm + w * 16 + col) * K;
    #pragma unroll
    for (int k0 = 0; k0 < K; k0 += 32) {
        float4 v0 = *(const float4*)(arow + k0 + quad * 8);
        float4 v1 = *(const float4*)(arow + k0 + quad * 8 + 4);
        BF8 af;
        af.e[0] = f2bf(v0.x); af.e[1] = f2bf(v0.y); af.e[2] = f2bf(v0.z); af.e[3] = f2bf(v0.w);
        af.e[4] = f2bf(v1.x); af.e[5] = f2bf(v1.y); af.e[6] = f2bf(v1.z); af.e[7] = f2bf(v1.w);
        #pragma unroll
        for (int nt = 0; nt < 8; nt++) {
            bf16x8 bf = *(const bf16x8*)(Bt + (size_t)(bn + nt * 16 + col) * K + k0 + quad * 8);
            acc[nt] = __builtin_amdgcn_mfma_f32_16x16x32_bf16(af.v, bf, acc[nt], 0, 0, 0);
        }
    }
    #pragma unroll
    for (int nt = 0; nt < 8; nt++) {
        int gn = bn + nt * 16 + col;
        float bv = bias[gn];
        #pragma unroll
        for (int r = 0; r < 4; r++) {
            int gm = bm + w * 16 + quad * 4 + r;
            Ch[(size_t)gm * N + gn] = f2bf(acc[nt][r] + bv);
        }
    }
}

// ---------------- MFMA GEMM, A = bf16, C = bf16 ------------------------------
__global__ __launch_bounds__(256) void gemm_mfma(const u16* __restrict__ A,
                                                 const u16* __restrict__ Bt,
                                                 const float* __restrict__ bias,
                                                 u16* __restrict__ Ch,
                                                 int N, int K) {
    int tid  = threadIdx.x;
    int w    = tid >> 6;
    int lane = tid & 63;
    int col  = lane & 15;
    int quad = lane >> 4;
    int bm = blockIdx.y * 64, bn = blockIdx.x * 128;

    f32x4 acc[8] = {};
    const u16* arow = A + (size_t)(bm + w * 16 + col) * K;
    #pragma unroll
    for (int k0 = 0; k0 < K; k0 += 32) {
        bf16x8 af = *(const bf16x8*)(arow + k0 + quad * 8);
        #pragma unroll
        for (int nt = 0; nt < 8; nt++) {
            bf16x8 bf = *(const bf16x8*)(Bt + (size_t)(bn + nt * 16 + col) * K + k0 + quad * 8);
            acc[nt] = __builtin_amdgcn_mfma_f32_16x16x32_bf16(af, bf, acc[nt], 0, 0, 0);
        }
    }
    #pragma unroll
    for (int nt = 0; nt < 8; nt++) {
        int gn = bn + nt * 16 + col;
        float bv = bias[gn];
        #pragma unroll
        for (int r = 0; r < 4; r++) {
            int gm = bm + w * 16 + quad * 4 + r;
            Ch[(size_t)gm * N + gn] = f2bf(acc[nt][r] + bv);
        }
    }
}

// ---------------- GRU scan (blocks 0..63) + zsum (blocks 64..127) ------------
// GRU: r10 structure (measured local optimum across 8 variants). zsum rides on
// CUs the 64-block GRU leaves idle (needs only zh -> no dependency on gi/gru).
__global__ __attribute__((amdgpu_flat_work_group_size(512, 512), amdgpu_waves_per_eu(2, 2)))
void gru_zsum_kernel(const u16* __restrict__ gi,
                     const uint2* __restrict__ Whh,
                     const float* __restrict__ bhn,
                     u16* __restrict__ ch,
                     const u16* __restrict__ zh,
                     float* __restrict__ zsum) {
    __shared__ __align__(16) char shraw[8704];
    int tid = threadIdx.x;          // 0..511

    if (blockIdx.x >= B_) {
        // ---- zsum[b][p] = sum_{t=1..T-1} z[b][t][p], 16-way t-split ---------
        float (*part)[128] = (float(*)[128])shraw;   // 8192 B
        int b   = blockIdx.x - B_;
        int pg  = tid & 31;
        int g   = tid >> 5;
        const u16* zb = zh + (size_t)b * T_ * P_;
        float s0 = 0.f, s1 = 0.f, s2 = 0.f, s3 = 0.f;
        for (int t = 1 + g; t < T_; t += 16) {
            uint2 v = *(const uint2*)(zb + (size_t)t * P_ + pg * 4);
            s0 += bflo(v.x); s1 += bfhi(v.x);
            s2 += bflo(v.y); s3 += bfhi(v.y);
        }
        part[g][pg * 4 + 0] = s0; part[g][pg * 4 + 1] = s1;
        part[g][pg * 4 + 2] = s2; part[g][pg * 4 + 3] = s3;
        __syncthreads();
        if (tid < 128) {
            float s = 0.f;
            #pragma unroll
            for (int g2 = 0; g2 < 16; g2++) s += part[g2][tid];
            zsum[(size_t)b * P_ + tid] = s;
        }
        return;
    }

    // ---- GRU: thread (j, half) owns gate cols j/j+256/j+512 for h-rows
    // [128*half, ...+128). 192 dw f16 weights/thread at 2 waves/SIMD. ---------
    _Float16* hbuf = (_Float16*)shraw;                       // 512 B
    float4 (*ps)[256] = (float4(*)[256])(shraw + 512);       // 8192 B
    int b    = blockIdx.x;
    int j    = tid & 255;
    int half = tid >> 8;

    uint2 wR[32], wZ[32], wN[32];
    {
        const uint2* base = Whh + (size_t)(half * 32) * 768;
        const uint2* cR = base + j;
        const uint2* cZ = base + 256 + j;
        const uint2* cN = base + 512 + j;
        #pragma unroll
        for (int i = 0; i < 32; i++) {
            wR[i] = cR[(size_t)i * 768];
            wZ[i] = cZ[(size_t)i * 768];
            wN[i] = cN[(size_t)i * 768];
        }
        #pragma unroll
        for (int i = 0; i < 32; i++) {
            asm volatile("" : "+v"(wR[i].x), "+v"(wR[i].y));
            asm volatile("" : "+v"(wZ[i].x), "+v"(wZ[i].y));
            asm volatile("" : "+v"(wN[i].x), "+v"(wN[i].y));
        }
    }
    if (tid < H_) hbuf[tid] = (_Float16)0.f;
    float bh = bhn[j];
    float hloc = 0.f;

    const u16* gib = gi + (size_t)b * T_ * 768;
    u16* cb = ch + (size_t)b * T_ * H_;
    float ir = 0.f, iz = 0.f, inn = 0.f;
    if (tid < 256) { ir = bf2f(gib[j]); iz = bf2f(gib[256 + j]); inn = bf2f(gib[512 + j]); }
    __syncthreads();

    const uint2* hw = (const uint2*)hbuf;
    #pragma unroll 1
    for (int t = 0; t < T_; t++) {
        float nir = 0.f, niz = 0.f, ninn = 0.f;
        if (tid < 256) {
            int tn = (t + 1 < T_) ? t + 1 : t;
            const u16* gtn = gib + (size_t)tn * 768;
            nir = bf2f(gtn[j]); niz = bf2f(gtn[256 + j]); ninn = bf2f(gtn[512 + j]);
        }
        float ar0 = 0.f, ar1 = 0.f, az0 = 0.f, az1 = 0.f, an0 = 0.f, an1 = 0.f;
        #pragma unroll
        for (int i = 0; i < 32; i++) {
            uint2 hv = hw[half * 32 + i];
            ar0 = dot2f16(hv.x, wR[i].x, ar0);
            ar1 = dot2f16(hv.y, wR[i].y, ar1);
            az0 = dot2f16(hv.x, wZ[i].x, az0);
            az1 = dot2f16(hv.y, wZ[i].y, az1);
            an0 = dot2f16(hv.x, wN[i].x, an0);
            an1 = dot2f16(hv.y, wN[i].y, an1);
        }
        ps[half][j] = make_float4(ar0 + ar1, az0 + az1, an0 + an1, 0.f);
        __syncthreads();
        if (tid < 256) {
            float4 p0 = ps[0][j], p1 = ps[1][j];
            float ar = p0.x + p1.x;
            float az = p0.y + p1.y;
            float an = p0.z + p1.z;
            float r   = rcpf(1.f + __expf(-(ir + ar)));
            float zg  = rcpf(1.f + __expf(-(iz + az)));
            float xn  = inn + r * (an + bh);
            float n   = fmaf(2.f, rcpf(1.f + __expf(-2.f * xn)), -1.f);
            hloc = (1.f - zg) * n + zg * hloc;
            cb[(size_t)t * H_ + j] = f2bf(hloc);
            hbuf[j] = (_Float16)hloc;
        }
        ir = nir; iz = niz; inn = ninn;
        __syncthreads();
    }
}

// ---------------- fused loss, MFMA; 128-row tiles; zh tiles staged in LDS ----
__global__ __launch_bounds__(512) void loss_fused(const u16* __restrict__ ch,
                                                  const u16* __restrict__ Wpt,
                                                  const float* __restrict__ bp,
                                                  const u16* __restrict__ zh,
                                                  const float* __restrict__ zsum,
                                                  float* __restrict__ accum) {
    __shared__ u16 Pst[128][136];
    __shared__ u16 Zt[64][136];
    __shared__ float sS[128];
    __shared__ float red[8];
    int k  = blockIdx.z + 1;
    int b  = blockIdx.y;
    int t0 = blockIdx.x * 128;
    int Tk = T_ - k;
    int tid  = threadIdx.x;
    int w    = tid >> 6;
    int lane = tid & 63;
    int col  = lane & 15;
    int quad = lane >> 4;
    const u16* zb = zh + (size_t)b * T_ * P_;

    // S_bk = zsum_b - sum_{t=1}^{k-1} z[t]
    if (tid < 128) {
        float s = zsum[(size_t)b * P_ + tid];
        for (int t = 1; t < k; t++) s -= bf2f(zb[(size_t)t * P_ + tid]);
        sS[tid] = s;
    }

    // ---- phase 1: Pst = bf16(ch-tile @ Wp[k] + bp[k]) -----------------------
    {
        f32x4 acc[8] = {};
        const u16* arow = ch + ((size_t)b * T_ + t0 + w * 16 + col) * H_;
        const u16* wk   = Wpt + (size_t)(k - 1) * P_ * H_;
        #pragma unroll
        for (int k0 = 0; k0 < 8; k0++) {
            bf16x8 af = *(const bf16x8*)(arow + k0 * 32 + quad * 8);
            #pragma unroll
            for (int nt = 0; nt < 8; nt++) {
                bf16x8 bf = *(const bf16x8*)(wk + (size_t)(nt * 16 + col) * H_ + k0 * 32 + quad * 8);
                acc[nt] = __builtin_amdgcn_mfma_f32_16x16x32_bf16(af, bf, acc[nt], 0, 0, 0);
            }
        }
        #pragma unroll
        for (int nt = 0; nt < 8; nt++) {
            float bias = bp[(size_t)(k - 1) * P_ + nt * 16 + col];
            #pragma unroll
            for (int r = 0; r < 4; r++)
                Pst[w * 16 + quad * 4 + r][nt * 16 + col] = f2bf(acc[nt][r] + bias);
        }
    }
    __syncthreads();

    // ---- phase 2: flash LSE over LDS-staged zh tiles ------------------------
    float mloc[4], sloc[4];
    #pragma unroll
    for (int r = 0; r < 4; r++) { mloc[r] = -INFINITY; sloc[r] = 0.f; }

    for (int ct = 0; ct < Tk; ct += 64) {
        __syncthreads();             // Zt free (prev tile's MFMAs done)
        {
            // 64 rows x 256 B = 16 KB contiguous; 512 thr x 2 x 16 B, coalesced
            int cc = tid;
            #pragma unroll
            for (int rep = 0; rep < 2; rep++, cc += 512) {
                int row = cc >> 4;
                int off = (cc & 15) * 8;
                int tcol = k + ct + row;     // may over-read into slack (masked)
                *(uint4*)&Zt[row][off] = *(const uint4*)(zb + (size_t)tcol * P_ + off);
            }
        }
        __syncthreads();
        f32x4 acc[4] = {};
        #pragma unroll
        for (int k0 = 0; k0 < 4; k0++) {
            bf16x8 af = *(const bf16x8*)(&Pst[w * 16 + col][k0 * 32 + quad * 8]);
            #pragma unroll
            for (int nt = 0; nt < 4; nt++) {
                bf16x8 bf = *(const bf16x8*)(&Zt[nt * 16 + col][k0 * 32 + quad * 8]);
                acc[nt] = __builtin_amdgcn_mfma_f32_16x16x32_bf16(af, bf, acc[nt], 0, 0, 0);
            }
        }
        #pragma unroll
        for (int r = 0; r < 4; r++) {
            float l[4];
            float tmax = -INFINITY;
            #pragma unroll
            for (int nt = 0; nt < 4; nt++) {
                bool valid = (ct + nt * 16 + col) < Tk;
                l[nt] = valid ? acc[nt][r] * INV_TEMP : -INFINITY;
                tmax = fmaxf(tmax, l[nt]);
            }
            float mnew = fmaxf(mloc[r], tmax);
            float e = __expf(l[0] - mnew) + __expf(l[1] - mnew)
                    + __expf(l[2] - mnew) + __expf(l[3] - mnew);
            sloc[r] = sloc[r] * __expf(mloc[r] - mnew) + e;
            mloc[r] = mnew;
        }
    }
    #pragma unroll
    for (int r = 0; r < 4; r++) {
        #pragma unroll
        for (int o = 1; o < 16; o <<= 1) {
            float mo = __shfl_xor(mloc[r], o, 64);
            float so = __shfl_xor(sloc[r], o, 64);
            float mn = fmaxf(mloc[r], mo);
            sloc[r] = sloc[r] * __expf(mloc[r] - mn) + so * __expf(mo - mn);
            mloc[r] = mn;
        }
    }
    float tkinv = INV_TEMP / (float)Tk;
    float scale = 1.0f / ((float)K_ * (float)B_ * (float)Tk);
    float bs = 0.f;
    #pragma unroll
    for (int r = 0; r < 4; r++) {
        int row = w * 16 + quad * 4 + r;
        BF8 pv;
        pv.v = *(const bf16x8*)(&Pst[row][col * 8]);
        float d = 0.f;
        #pragma unroll
        for (int m = 0; m < 8; m++) d = fmaf(bf2f(pv.e[m]), sS[col * 8 + m], d);
        #pragma unroll
        for (int o = 1; o < 16; o <<= 1) d += __shfl_xor(d, o, 64);
        int gr = t0 + row;
        if (gr < Tk) bs += mloc[r] + __logf(sloc[r]) - d * tkinv;
    }
    if (col != 0) bs = 0.f;
    bs = wave_sum(bs);
    if (lane == 0) red[w] = bs;
    __syncthreads();
    if (tid == 0) {
        float tot = 0.f;
        #pragma unroll
        for (int i = 0; i < 8; i++) tot += red[i];
        atomicAdd(&accum[(blockIdx.x * 809 + b * 67 + blockIdx.z * 131) & 1023],
                  tot * scale);
    }
}

__global__ void finalize(const float* __restrict__ accum, float* __restrict__ out) {
    int tid = threadIdx.x;
    __shared__ float red[4];
    float v = 0.f;
    for (int i = tid; i < 1024; i += 256) v += accum[i];
    float sres = wave_sum(v);
    if ((tid & 63) == 0) red[tid >> 6] = sres;
    __syncthreads();
    if (tid == 0) out[0] = red[0] + red[1] + red[2] + red[3];
}

// ---------------- launch -----------------------------------------------------
extern "C" void kernel_launch(void* const* d_in, const int* in_sizes, int n_in,
                              void* d_out, int out_size, void* d_ws, size_t ws_size,
                              hipStream_t stream) {
    const float* x      = (const float*)d_in[0];
    const float* W_enc  = (const float*)d_in[1];
    const float* b_enc  = (const float*)d_in[2];
    const float* W_proj = (const float*)d_in[3];
    const float* b_proj = (const float*)d_in[4];
    const float* Wi     = (const float*)d_in[5];
    const float* bi     = (const float*)d_in[6];
    const float* Wh     = (const float*)d_in[7];
    const float* bhn    = (const float*)d_in[8];
    const float* Wp     = (const float*)d_in[9];
    const float* bp     = (const float*)d_in[10];
    float* out = (float*)d_out;

    // layout (float offsets)
    float* ws    = (float*)d_ws;
    float* bc    = ws;                          // 128
    float* accum = bc + 128;                    // 1024 -> end 1152
    uint2* Whh   = (uint2*)(ws + 1152);         // 49152 uint2 = 98304 fl -> end 99456
    u16* Wct     = (u16*)(ws + 99456);          // 16384 fl -> end 115840
    u16* Wit     = (u16*)(ws + 115840);         // 49152 fl -> end 164992
    u16* Wpt     = (u16*)(ws + 164992);         // 196608 fl -> end 361600
    u16* zh      = (u16*)(ws + 361600);         // 2097152 fl -> end 2458752
    float* zsum  = ws + 2458752;                // 8192 fl (doubles as zh over-read slack) -> end 2466944
    u16* gi      = (u16*)(ws + 2466944);        // 12582912 fl -> end 15049856
    u16* ch      = (u16*)(ws + 15049856);       // 4194304 fl -> end 19244160 (~77 MB)

    const int MT = B_ * T_;                     // 32768

    // merged setup: all weight conversions + fold + accum zero (801 blocks)
    setup_conv<<<801, 256, 0, stream>>>(Wh, Whh, Wi, Wit, Wp, Wpt,
                                        W_enc, b_enc, W_proj, b_proj, Wct, bc, accum);
    // zh = bf16(x @ Wct^T + bc)   (M=32768, N=128, K=256; A converted in-reg)
    gemm_mfma_f32a<<<dim3(1, MT / 64), 256, 0, stream>>>(x, Wct, bc, zh, P_, F_);
    // gi = bf16(zh @ Wit^T + bi)  (M=32768, N=768, K=128)
    gemm_mfma<<<dim3(6, MT / 64), 256, 0, stream>>>(zh, Wit, bi, gi, 3 * H_, P_);
    // GRU scan -> ch (blocks 0..63, dot2 — measured optimum) + zsum (64..127)
    gru_zsum_kernel<<<2 * B_, 512, 0, stream>>>(gi, Whh, bhn, ch, zh, zsum);
    // fused pred-GEMM + flash loss (MFMA), 128-row tiles, LDS-staged zh
    loss_fused<<<dim3(4, B_, K_), 512, 0, stream>>>(ch, Wpt, bp, zh, zsum, accum);
    finalize<<<1, 256, 0, stream>>>(accum, out);
}